// Round 3
// baseline (547.269 us; speedup 1.0000x reference)
//
#include <hip/hip_runtime.h>
#include <hip/hip_cooperative_groups.h>
#include <math.h>

namespace cg = cooperative_groups;

// ElectronicEmbedding (SpookyNet), MI355X.
// Rank-1: y_n = coef_n * Wv (scalar per atom) => MLP output is 1-D G(coef);
// tabulate G (mtab pts) + lerp. dot_n = (e/enorm)/16 * (u.x_n + c0), u=Wq^T Wk.
// R6: R5 cooperative mega-fusion, fixed compile (hipDeviceAttributeMultiprocessorCount).
// Single kernel dot -> (grid.sync) -> per-block redundant cmax -> table build
// (blocks 0..mtab/PTS-1) -> (grid.sync) -> out. a-stash in LDS, k_bmax gone,
// 3 launch gaps gone. Grid sized by occupancy query; fallback to the R4
// multi-kernel path if coop unsupported / stash overflow.

#define F 256
#define PTS 4

typedef unsigned short u16;
typedef unsigned int u32;

__device__ __forceinline__ float b2f(u16 u) {
    union { u32 i; float f; } v; v.i = ((u32)u) << 16; return v.f;
}
__device__ __forceinline__ u16 f2b(float f) {
    union { float f; u32 i; } v; v.f = f;
    u32 r = 0x7fffu + ((v.i >> 16) & 1u);
    return (u16)((v.i + r) >> 16);
}
__device__ __forceinline__ float silu_(float v) { return v / (1.f + __expf(-v)); }
__device__ __forceinline__ float loadf(const void* p, size_t i, int f32) {
    return f32 ? ((const float*)p)[i] : b2f(((const u16*)p)[i]);
}
__device__ __forceinline__ int loadseg(const int* seg, int n, int i64) {
    return i64 ? seg[2 * n] : seg[n];
}

// ---------------- K1: dtype detect + uvec prep (both paths) ----------------
__global__ __launch_bounds__(256) void k_prep(const u16* __restrict__ xr,
                                              const int* __restrict__ seg,
                                              const void* __restrict__ Wq,
                                              const void* __restrict__ bq,
                                              const void* __restrict__ Wk,
                                              u32* __restrict__ flag,
                                              float* __restrict__ uvec) {
    int t = threadIdx.x;
    __shared__ int redw[256], redz[256];
    int weird = 0;
    #pragma unroll
    for (int i = 0; i < 16; ++i) {
        u16 u = xr[t * 16 + i];
        u32 e = (u >> 7) & 0xFF;
        weird += (e >= 0xC0) ? 1 : 0;
    }
    redw[t] = weird;
    redz[t] = (seg[2 * t + 1] == 0) ? 1 : 0;
    __syncthreads();
    for (int s = 128; s > 0; s >>= 1) {
        if (t < s) { redw[t] += redw[t + s]; redz[t] += redz[t + s]; }
        __syncthreads();
    }
    u32 fl = ((redw[0] > 64) ? 1u : 0u) | ((redz[0] >= 200) ? 2u : 0u);
    if (blockIdx.x == 0 && t == 0) flag[0] = fl;
    int f32 = (int)(fl & 1u);
    int j = t;
    int f0 = blockIdx.x * 8;
    float acc = 0.f;
    for (int f = f0; f < f0 + 8; ++f)
        acc += loadf(Wk, f, f32) * loadf(Wq, (size_t)f * F + j, f32);
    atomicAdd(&uvec[j], acc);
    if (blockIdx.x == 0) {
        __shared__ float red[256];
        red[j] = loadf(Wk, j, f32) * loadf(bq, j, f32);
        __syncthreads();
        for (int s = 128; s > 0; s >>= 1) {
            if (j < s) red[j] += red[j + s];
            __syncthreads();
        }
        if (j == 0) uvec[F] = red[0];
    }
}

// ---------------- shared matvec for table build ----------------
template <int DT>
__device__ __forceinline__ void matvec(const void* __restrict__ W, size_t off,
                                       const float4* __restrict__ act, float* g) {
    #pragma unroll 4
    for (int f8 = 0; f8 < F; f8 += 8) {
        float w[8];
        if (DT) {
            const float* Wf = (const float*)W + off + f8;
            float4 w0 = *(const float4*)Wf;
            float4 w1 = *(const float4*)(Wf + 4);
            w[0] = w0.x; w[1] = w0.y; w[2] = w0.z; w[3] = w0.w;
            w[4] = w1.x; w[5] = w1.y; w[6] = w1.z; w[7] = w1.w;
        } else {
            uint4 wv = *(const uint4*)((const u16*)W + off + f8);
            w[0] = b2f((u16)(wv.x & 0xffff)); w[1] = b2f((u16)(wv.x >> 16));
            w[2] = b2f((u16)(wv.y & 0xffff)); w[3] = b2f((u16)(wv.y >> 16));
            w[4] = b2f((u16)(wv.z & 0xffff)); w[5] = b2f((u16)(wv.z >> 16));
            w[6] = b2f((u16)(wv.w & 0xffff)); w[7] = b2f((u16)(wv.w >> 16));
        }
        #pragma unroll
        for (int q = 0; q < 8; ++q) {
            float4 a = act[f8 + q];
            g[0] += a.x * w[q]; g[1] += a.y * w[q];
            g[2] += a.z * w[q]; g[3] += a.w * w[q];
        }
    }
}

// ==================== FUSED cooperative kernel ====================
template <int DT>
__device__ void fused_body(const char* __restrict__ x, const void* __restrict__ E,
                           const int* __restrict__ seg, int i64,
                           const float* __restrict__ uvec, char* __restrict__ out,
                           float* __restrict__ anorm, u32* __restrict__ amax,
                           float* __restrict__ table,
                           const void* __restrict__ Wv, const void* __restrict__ W1,
                           const void* __restrict__ W2, const void* __restrict__ Wo,
                           int N, int B, int R, int mtab, int gpb,
                           float* stash, float4* actA, float4* actB,
                           float* red, float* s_cmax) {
    cg::grid_group gridg = cg::this_grid();
    const int tid = threadIdx.x;
    const int lane = tid & 63;
    const int o = lane & 15, g = lane >> 4;
    const int wvb = tid >> 6;                 // wave in block 0..3
    const int g0 = blockIdx.x * gpb;
    const size_t rowbytes = (size_t)F * (DT ? 4 : 2);

    float uf[16];
    if (DT) {
        #pragma unroll
        for (int i = 0; i < 4; ++i)
            *(float4*)&uf[i * 4] = *(const float4*)(uvec + (o + 16 * i) * 4);
    } else {
        #pragma unroll
        for (int i = 0; i < 2; ++i) {
            int eo = (o + 16 * i) * 8;
            *(float4*)&uf[i * 8]     = *(const float4*)(uvec + eo);
            *(float4*)&uf[i * 8 + 4] = *(const float4*)(uvec + eo + 4);
        }
    }
    const float c0 = uvec[F];

    // ---- Phase A: dot + softplus, stash a in LDS, segmented atomics ----
    for (int gg = wvb; gg < gpb; gg += 4) {
        const int row = (g0 + gg) * 4 + g;
        float s = 0.f;
        if (row < N) {
            const char* rp = x + (size_t)row * rowbytes;
            if (DT) {
                #pragma unroll
                for (int i = 0; i < 4; ++i) {
                    float4 v = *(const float4*)(rp + (size_t)(o + 16 * i) * 16);
                    s += v.x * uf[i*4] + v.y * uf[i*4+1] + v.z * uf[i*4+2] + v.w * uf[i*4+3];
                }
            } else {
                #pragma unroll
                for (int i = 0; i < 2; ++i) {
                    uint4 v = *(const uint4*)(rp + (size_t)(o + 16 * i) * 16);
                    const u32 w[4] = {v.x, v.y, v.z, v.w};
                    #pragma unroll
                    for (int k = 0; k < 4; ++k) {
                        s += b2f((u16)(w[k] & 0xffff)) * uf[i*8 + 2*k];
                        s += b2f((u16)(w[k] >> 16))    * uf[i*8 + 2*k + 1];
                    }
                }
            }
        }
        s += __shfl_xor(s, 1, 64);
        s += __shfl_xor(s, 2, 64);
        s += __shfl_xor(s, 4, 64);
        s += __shfl_xor(s, 8, 64);
        float a = 0.f; int b = 0x7fffffff;
        if (o == 0 && row < N) {
            b = loadseg(seg, row, i64);
            float e = fabsf(loadf(E, b, DT));
            float dot = (e / fmaxf(e, 1.f)) * (s + c0) * 0.0625f;
            a = fmaxf(dot, 0.f) + log1pf(expf(-fabsf(dot)));
            stash[gg * 4 + g] = a;
        }
        // segmented suffix-combine across the 4 owner lanes (seg sorted)
        float rs = a, rm = a;
        #pragma unroll
        for (int off = 16; off <= 32; off <<= 1) {
            float rs2 = __shfl_down(rs, off, 64);
            float rm2 = __shfl_down(rm, off, 64);
            int   b2  = __shfl_down(b, off, 64);
            if (lane + off < 64 && b2 == b) { rs += rs2; rm = fmaxf(rm, rm2); }
        }
        int bprev = __shfl_up(b, 16, 64);
        if (o == 0 && row < N && (g == 0 || bprev != b)) {
            atomicAdd(&anorm[b], rs);
            atomicMax(&amax[b], __float_as_uint(rm));   // a >= 0
        }
    }

    gridg.sync();

    // ---- Phase B: per-block redundant cmax (bit-identical everywhere) ----
    {
        float m = 0.f;
        for (int b = tid; b < B; b += 256)
            m = fmaxf(m, __uint_as_float(amax[b]) * fabsf(loadf(E, b, DT)) / (anorm[b] + 1e-8f));
        red[tid] = m;
        __syncthreads();
        for (int s2 = 128; s2 > 0; s2 >>= 1) {
            if (tid < s2) red[tid] = fmaxf(red[tid], red[tid + s2]);
            __syncthreads();
        }
        if (tid == 0) *s_cmax = red[0];
        __syncthreads();
    }
    const float cmax = *s_cmax;

    // ---- Phase C: table build (blocks 0..mtab/PTS-1) ----
    if ((int)blockIdx.x * PTS < mtab) {
        const int j = tid;
        const int i0 = blockIdx.x * PTS;
        float h[PTS], gacc[PTS];
        float wvj = loadf(Wv, j, DT);
        #pragma unroll
        for (int p = 0; p < PTS; ++p)
            h[p] = cmax * ((float)(i0 + p) / (float)(mtab - 1)) * wvj;
        for (int r = 0; r < R; ++r) {
            size_t off = (size_t)r * F * F + (size_t)j * F;
            actA[j] = make_float4(silu_(h[0]), silu_(h[1]), silu_(h[2]), silu_(h[3]));
            __syncthreads();
            #pragma unroll
            for (int p = 0; p < PTS; ++p) gacc[p] = 0.f;
            matvec<DT>(W1, off, actA, gacc);
            actB[j] = make_float4(silu_(gacc[0]), silu_(gacc[1]), silu_(gacc[2]), silu_(gacc[3]));
            __syncthreads();
            matvec<DT>(W2, off, actB, h);
            __syncthreads();
        }
        actA[j] = make_float4(silu_(h[0]), silu_(h[1]), silu_(h[2]), silu_(h[3]));
        __syncthreads();
        #pragma unroll
        for (int p = 0; p < PTS; ++p) gacc[p] = 0.f;
        matvec<DT>(Wo, (size_t)j * F, actA, gacc);
        #pragma unroll
        for (int p = 0; p < PTS; ++p) table[(size_t)(i0 + p) * F + j] = gacc[p];
    }

    gridg.sync();

    // ---- Phase D: lerp + full-row write ----
    for (int gg = wvb; gg < gpb; gg += 4) {
        const int row = (g0 + gg) * 4 + g;
        if (row >= N) continue;
        char* rp = out + (size_t)row * rowbytes;
        float a = stash[gg * 4 + g];
        int b = loadseg(seg, row, i64);
        float e = fabsf(loadf(E, b, DT));
        float c = a * e / (anorm[b] + 1e-8f);
        float pos = (cmax > 0.f) ? (c / cmax) * (float)(mtab - 1) : 0.f;
        pos = fminf(fmaxf(pos, 0.f), (float)(mtab - 1));
        int idx = (int)pos;
        if (idx > mtab - 2) idx = mtab - 2;
        float fr = pos - (float)idx;
        const float* t0 = table + (size_t)idx * F;
        const float* t1 = t0 + F;
        if (DT) {
            #pragma unroll
            for (int i = 0; i < 4; ++i) {
                int eo = (o + 16 * i) * 4;
                float4 u0 = *(const float4*)(t0 + eo);
                float4 u1 = *(const float4*)(t1 + eo);
                float4 ov;
                ov.x = u0.x + fr * (u1.x - u0.x);
                ov.y = u0.y + fr * (u1.y - u0.y);
                ov.z = u0.z + fr * (u1.z - u0.z);
                ov.w = u0.w + fr * (u1.w - u0.w);
                *(float4*)(rp + (size_t)eo * 4) = ov;
            }
        } else {
            #pragma unroll
            for (int i = 0; i < 2; ++i) {
                int eo = (o + 16 * i) * 8;
                float4 u0 = *(const float4*)(t0 + eo);
                float4 u1 = *(const float4*)(t1 + eo);
                float4 v0 = *(const float4*)(t0 + eo + 4);
                float4 v1 = *(const float4*)(t1 + eo + 4);
                uint4 ov;
                ov.x = (u32)f2b(u0.x + fr * (u1.x - u0.x)) | ((u32)f2b(u0.y + fr * (u1.y - u0.y)) << 16);
                ov.y = (u32)f2b(u0.z + fr * (u1.z - u0.z)) | ((u32)f2b(u0.w + fr * (u1.w - u0.w)) << 16);
                ov.z = (u32)f2b(v0.x + fr * (v1.x - v0.x)) | ((u32)f2b(v0.y + fr * (v1.y - v0.y)) << 16);
                ov.w = (u32)f2b(v0.z + fr * (v1.z - v0.z)) | ((u32)f2b(v0.w + fr * (v1.w - v0.w)) << 16);
                *(uint4*)(rp + (size_t)eo * 2) = ov;
            }
        }
    }
}

__global__ __launch_bounds__(256, 4) void k_fused(
        const void* x, const void* E, const int* seg, const u32* flag,
        const float* uvec, void* out, float* anorm, u32* amax, float* table,
        const void* Wv, const void* W1, const void* W2, const void* Wo,
        int N, int B, int R, int mtab, int gpb) {
    __shared__ float stash[1024];
    __shared__ float4 actA[F];
    __shared__ float4 actB[F];
    __shared__ float red[256];
    __shared__ float s_cmax;
    u32 fl = flag[0];
    if (fl & 1u)
        fused_body<1>((const char*)x, E, seg, (int)(fl >> 1), uvec, (char*)out,
                      anorm, amax, table, Wv, W1, W2, Wo, N, B, R, mtab, gpb,
                      stash, actA, actB, red, &s_cmax);
    else
        fused_body<0>((const char*)x, E, seg, (int)(fl >> 1), uvec, (char*)out,
                      anorm, amax, table, Wv, W1, W2, Wo, N, B, R, mtab, gpb,
                      stash, actA, actB, red, &s_cmax);
}

// ==================== FALLBACK multi-kernel path (R4) ====================
template <int DT>
__device__ void dot_body(const char* __restrict__ x, const void* __restrict__ E,
                         const int* __restrict__ seg, int i64,
                         const float* __restrict__ uvec, char* __restrict__ out,
                         float* __restrict__ anorm, u32* __restrict__ amax, int N) {
    const int lane = threadIdx.x & 63;
    const int o = lane & 15, g = lane >> 4;
    const int wid = (blockIdx.x * blockDim.x + threadIdx.x) >> 6;
    const int nw = (gridDim.x * blockDim.x) >> 6;
    const int ngrp = (N + 3) >> 2;
    float uf[16];
    if (DT) {
        #pragma unroll
        for (int i = 0; i < 4; ++i)
            *(float4*)&uf[i * 4] = *(const float4*)(uvec + (o + 16 * i) * 4);
    } else {
        #pragma unroll
        for (int i = 0; i < 2; ++i) {
            int eo = (o + 16 * i) * 8;
            *(float4*)&uf[i * 8]     = *(const float4*)(uvec + eo);
            *(float4*)&uf[i * 8 + 4] = *(const float4*)(uvec + eo + 4);
        }
    }
    const float c0 = uvec[F];
    const size_t rowbytes = (size_t)F * (DT ? 4 : 2);
    for (int grp = wid; grp < ngrp; grp += nw) {
        const int row = grp * 4 + g;
        float s = 0.f;
        if (row < N) {
            const char* rp = x + (size_t)row * rowbytes;
            if (DT) {
                #pragma unroll
                for (int i = 0; i < 4; ++i) {
                    float4 v = *(const float4*)(rp + (size_t)(o + 16 * i) * 16);
                    s += v.x * uf[i*4] + v.y * uf[i*4+1] + v.z * uf[i*4+2] + v.w * uf[i*4+3];
                }
            } else {
                #pragma unroll
                for (int i = 0; i < 2; ++i) {
                    uint4 v = *(const uint4*)(rp + (size_t)(o + 16 * i) * 16);
                    const u32 w[4] = {v.x, v.y, v.z, v.w};
                    #pragma unroll
                    for (int k = 0; k < 4; ++k) {
                        s += b2f((u16)(w[k] & 0xffff)) * uf[i*8 + 2*k];
                        s += b2f((u16)(w[k] >> 16))    * uf[i*8 + 2*k + 1];
                    }
                }
            }
        }
        s += __shfl_xor(s, 1, 64);
        s += __shfl_xor(s, 2, 64);
        s += __shfl_xor(s, 4, 64);
        s += __shfl_xor(s, 8, 64);
        float a = 0.f; int b = 0x7fffffff;
        if (o == 0 && row < N) {
            b = loadseg(seg, row, i64);
            float e = fabsf(loadf(E, b, DT));
            float dot = (e / fmaxf(e, 1.f)) * (s + c0) * 0.0625f;
            a = fmaxf(dot, 0.f) + log1pf(expf(-fabsf(dot)));
            *(float*)(out + (size_t)row * rowbytes) = a;
        }
        float rs = a, rm = a;
        #pragma unroll
        for (int off = 16; off <= 32; off <<= 1) {
            float rs2 = __shfl_down(rs, off, 64);
            float rm2 = __shfl_down(rm, off, 64);
            int   b2  = __shfl_down(b, off, 64);
            if (lane + off < 64 && b2 == b) { rs += rs2; rm = fmaxf(rm, rm2); }
        }
        int bprev = __shfl_up(b, 16, 64);
        if (o == 0 && row < N && (g == 0 || bprev != b)) {
            atomicAdd(&anorm[b], rs);
            atomicMax(&amax[b], __float_as_uint(rm));
        }
    }
}

__global__ __launch_bounds__(256) void k_dot(const void* x, const void* E,
                                             const int* seg, const u32* flag,
                                             const float* uvec, void* out,
                                             float* anorm, u32* amax, int N) {
    u32 fl = flag[0];
    if (fl & 1u) dot_body<1>((const char*)x, E, seg, (int)(fl >> 1), uvec, (char*)out, anorm, amax, N);
    else         dot_body<0>((const char*)x, E, seg, (int)(fl >> 1), uvec, (char*)out, anorm, amax, N);
}

__global__ __launch_bounds__(256) void k_bmax(const void* __restrict__ E,
                                              const u32* __restrict__ flag,
                                              const float* __restrict__ anorm,
                                              const u32* __restrict__ amax,
                                              u32* __restrict__ cmax, int B) {
    int f32 = (int)(flag[0] & 1u);
    float m = 0.f;
    for (int b = blockIdx.x * 256 + threadIdx.x; b < B; b += gridDim.x * 256)
        m = fmaxf(m, __uint_as_float(amax[b]) * fabsf(loadf(E, b, f32)) / (anorm[b] + 1e-8f));
    #pragma unroll
    for (int off = 32; off > 0; off >>= 1) m = fmaxf(m, __shfl_down(m, off, 64));
    if ((threadIdx.x & 63) == 0) atomicMax(cmax, __float_as_uint(m));
}

template <int DT>
__device__ void table_body(const void* Wv, const void* W1, const void* W2,
                           const void* Wo, float cmax, float* table, int R, int mtab) {
    int j = threadIdx.x;
    int i0 = blockIdx.x * PTS;
    __shared__ float4 actA[F];
    __shared__ float4 actB[F];
    float h[PTS], g[PTS];
    float wvj = loadf(Wv, j, DT);
    #pragma unroll
    for (int p = 0; p < PTS; ++p)
        h[p] = cmax * ((float)(i0 + p) / (float)(mtab - 1)) * wvj;
    for (int r = 0; r < R; ++r) {
        size_t o = (size_t)r * F * F + (size_t)j * F;
        actA[j] = make_float4(silu_(h[0]), silu_(h[1]), silu_(h[2]), silu_(h[3]));
        __syncthreads();
        #pragma unroll
        for (int p = 0; p < PTS; ++p) g[p] = 0.f;
        matvec<DT>(W1, o, actA, g);
        actB[j] = make_float4(silu_(g[0]), silu_(g[1]), silu_(g[2]), silu_(g[3]));
        __syncthreads();
        matvec<DT>(W2, o, actB, h);
        __syncthreads();
    }
    actA[j] = make_float4(silu_(h[0]), silu_(h[1]), silu_(h[2]), silu_(h[3]));
    __syncthreads();
    #pragma unroll
    for (int p = 0; p < PTS; ++p) g[p] = 0.f;
    matvec<DT>(Wo, (size_t)j * F, actA, g);
    #pragma unroll
    for (int p = 0; p < PTS; ++p) table[(size_t)(i0 + p) * F + j] = g[p];
}

__global__ __launch_bounds__(256) void k_table(const void* Wv, const void* W1,
                                               const void* W2, const void* Wo,
                                               const u32* __restrict__ flag,
                                               const u32* __restrict__ cmaxu,
                                               float* __restrict__ table, int R, int mtab) {
    float cmax = __uint_as_float(cmaxu[0]);
    if (flag[0] & 1u) table_body<1>(Wv, W1, W2, Wo, cmax, table, R, mtab);
    else              table_body<0>(Wv, W1, W2, Wo, cmax, table, R, mtab);
}

template <int DT>
__device__ void out_body(const void* __restrict__ E, const int* __restrict__ seg,
                         int i64, const float* __restrict__ anorm,
                         const float* __restrict__ table, float cmax,
                         char* __restrict__ out, int N, int mtab) {
    const int lane = threadIdx.x & 63;
    const int o = lane & 15, g = lane >> 4;
    const int wid = (blockIdx.x * blockDim.x + threadIdx.x) >> 6;
    const int nw = (gridDim.x * blockDim.x) >> 6;
    const int ngrp = (N + 3) >> 2;
    const size_t rowbytes = (size_t)F * (DT ? 4 : 2);
    for (int grp = wid; grp < ngrp; grp += nw) {
        const int row = grp * 4 + g;
        if (row >= N) continue;
        char* rp = out + (size_t)row * rowbytes;
        float a = *(const float*)rp;
        int b = loadseg(seg, row, i64);
        float e = fabsf(loadf(E, b, DT));
        float c = a * e / (anorm[b] + 1e-8f);
        float pos = (cmax > 0.f) ? (c / cmax) * (float)(mtab - 1) : 0.f;
        pos = fminf(fmaxf(pos, 0.f), (float)(mtab - 1));
        int idx = (int)pos;
        if (idx > mtab - 2) idx = mtab - 2;
        float fr = pos - (float)idx;
        const float* t0 = table + (size_t)idx * F;
        const float* t1 = t0 + F;
        if (DT) {
            #pragma unroll
            for (int i = 0; i < 4; ++i) {
                int eo = (o + 16 * i) * 4;
                float4 u0 = *(const float4*)(t0 + eo);
                float4 u1 = *(const float4*)(t1 + eo);
                float4 ov;
                ov.x = u0.x + fr * (u1.x - u0.x);
                ov.y = u0.y + fr * (u1.y - u0.y);
                ov.z = u0.z + fr * (u1.z - u0.z);
                ov.w = u0.w + fr * (u1.w - u0.w);
                *(float4*)(rp + (size_t)eo * 4) = ov;
            }
        } else {
            #pragma unroll
            for (int i = 0; i < 2; ++i) {
                int eo = (o + 16 * i) * 8;
                float4 u0 = *(const float4*)(t0 + eo);
                float4 u1 = *(const float4*)(t1 + eo);
                float4 v0 = *(const float4*)(t0 + eo + 4);
                float4 v1 = *(const float4*)(t1 + eo + 4);
                uint4 ov;
                ov.x = (u32)f2b(u0.x + fr * (u1.x - u0.x)) | ((u32)f2b(u0.y + fr * (u1.y - u0.y)) << 16);
                ov.y = (u32)f2b(u0.z + fr * (u1.z - u0.z)) | ((u32)f2b(u0.w + fr * (u1.w - u0.w)) << 16);
                ov.z = (u32)f2b(v0.x + fr * (v1.x - v0.x)) | ((u32)f2b(v0.y + fr * (v1.y - v0.y)) << 16);
                ov.w = (u32)f2b(v0.z + fr * (v1.z - v0.z)) | ((u32)f2b(v0.w + fr * (v1.w - v0.w)) << 16);
                *(uint4*)(rp + (size_t)eo * 2) = ov;
            }
        }
    }
}

__global__ __launch_bounds__(256) void k_out(const void* E, const int* seg,
                                             const u32* flag, const float* anorm,
                                             const float* table, const u32* cmaxu,
                                             void* out, int N, int mtab) {
    u32 fl = flag[0];
    float cmax = __uint_as_float(cmaxu[0]);
    if (fl & 1u) out_body<1>(E, seg, (int)(fl >> 1), anorm, table, cmax, (char*)out, N, mtab);
    else         out_body<0>(E, seg, (int)(fl >> 1), anorm, table, cmax, (char*)out, N, mtab);
}

// ==================== host launcher ====================
extern "C" void kernel_launch(void* const* d_in, const int* in_sizes, int n_in,
                              void* d_out, int out_size, void* d_ws, size_t ws_size,
                              hipStream_t stream) {
    int si = (in_sizes[2] == 1) ? 3 : 2;  // batch_seg index (scalar may be dropped)
    const void* x   = d_in[0];
    const void* E   = d_in[1];
    const int* seg  = (const int*)d_in[si];
    const void* Wq  = d_in[si + 1];
    const void* bq  = d_in[si + 2];
    const void* Wk  = d_in[si + 3];
    const void* Wv  = d_in[si + 4];
    const void* W1  = d_in[si + 5];
    const void* W2  = d_in[si + 6];
    const void* Wo  = d_in[si + 7];

    const int B = in_sizes[1];
    const int N = in_sizes[0] / F;
    const int R = in_sizes[si + 5] / (F * F);

    float* ws    = (float*)d_ws;
    float* uvec  = ws;                    // [0..257)
    u32*   cmaxu = (u32*)ws + 258;
    u32*   flag  = (u32*)ws + 259;
    float* anorm = ws + 512;              // B floats
    u32*   amax  = (u32*)ws + 512 + B;    // B u32
    size_t tof   = (size_t)(512 + 2 * B + 64);
    if (tof < 8192) tof = 8192;
    float* table = ws + tof;

    size_t avail = (ws_size > tof * 4) ? ws_size - tof * 4 : 0;
    int mtab = 1024;
    while (mtab > 32 && (size_t)mtab * F * sizeof(float) > avail) mtab >>= 1;

    // one-time device queries (attribute queries only; capture-safe)
    static int s_init = 0, s_coop = 0, s_cu = 0, s_maxb = 0;
    if (!s_init) {
        int dev = 0;
        (void)hipGetDevice(&dev);
        (void)hipDeviceGetAttribute(&s_coop, hipDeviceAttributeCooperativeLaunch, dev);
        (void)hipDeviceGetAttribute(&s_cu, hipDeviceAttributeMultiprocessorCount, dev);
        (void)hipOccupancyMaxActiveBlocksPerMultiprocessor(&s_maxb,
            reinterpret_cast<const void*>(k_fused), 256, 0);
        s_init = 1;
    }

    (void)hipMemsetAsync(ws, 0, tof * 4, stream);  // zeroes uvec, cmax, flag, anorm, amax
    k_prep<<<32, 256, 0, stream>>>((const u16*)x, seg, Wq, bq, Wk, flag, uvec);

    const int ngrp = (N + 3) / 4;
    bool coop = (s_coop > 0) && (s_maxb >= 1) && (s_cu > 0);
    int gridb = 0, gpb = 0;
    if (coop) {
        int nb = s_maxb > 8 ? 8 : s_maxb;
        gridb = nb * s_cu;
        if (gridb > ngrp) gridb = ngrp > 0 ? ngrp : 1;
        gpb = (ngrp + gridb - 1) / gridb;
        if (gpb * 4 > 1024) coop = false;               // LDS stash capacity
        if (gridb < mtab / PTS) coop = false;           // table blocks must exist
    }

    if (coop) {
        void* outp = d_out;
        int N_ = N, B_ = B, R_ = R, mtab_ = mtab, gpb_ = gpb;
        void* params[] = {
            (void*)&x, (void*)&E, (void*)&seg, (void*)&flag, (void*)&uvec,
            (void*)&outp, (void*)&anorm, (void*)&amax, (void*)&table,
            (void*)&Wv, (void*)&W1, (void*)&W2, (void*)&Wo,
            (void*)&N_, (void*)&B_, (void*)&R_, (void*)&mtab_, (void*)&gpb_ };
        hipError_t err = hipLaunchCooperativeKernel(
            reinterpret_cast<const void*>(k_fused),
            dim3(gridb), dim3(256), params, 0, stream);
        if (err == hipSuccess) return;
        // fall through to multi-kernel path on any launch validation failure
    }

    int blocks = (ngrp + 15) / 16; if (blocks > 2048) blocks = 2048;
    k_dot<<<blocks, 256, 0, stream>>>(x, E, seg, flag, uvec, d_out, anorm, amax, N);
    k_bmax<<<8, 256, 0, stream>>>(E, flag, anorm, amax, cmaxu, B);
    k_table<<<mtab / PTS, 256, 0, stream>>>(Wv, W1, W2, Wo, flag, cmaxu, table, R, mtab);
    k_out<<<blocks, 256, 0, stream>>>(E, seg, flag, anorm, table, cmaxu, d_out, N, mtab);
}

// Round 5
// 442.551 us; speedup vs baseline: 1.2366x; 1.2366x over previous
//
#include <hip/hip_runtime.h>
#include <math.h>

// ElectronicEmbedding (SpookyNet), MI355X.
// Rank-1: y_n = coef_n * Wv (scalar per atom) => MLP output is 1-D G(coef);
// tabulate G (mtab pts) + lerp. dot_n = (e/enorm)/16 * (u.x_n + c0), u=Wq^T Wk.
// R8: resubmit of R7 (container infra failure, kernel never ran).
// Revert coop fusion (grid.sync + phase serialization cost > launch gaps).
// Attack the atomic storm instead: k_dot is block-chunked over sorted rows with
// an LDS batch-window pre-reduction (16x fewer global atomics); a-stash moved
// to a compact ws array (d_out pure write-only, no scattered 64B stash reads);
// k_bmax folded into k_table prologue (block 0 publishes cmaxu for k_out).

#define F 256
#define PTS 4
#define WIN 128

typedef unsigned short u16;
typedef unsigned int u32;

__device__ __forceinline__ float b2f(u16 u) {
    union { u32 i; float f; } v; v.i = ((u32)u) << 16; return v.f;
}
__device__ __forceinline__ u16 f2b(float f) {
    union { float f; u32 i; } v; v.f = f;
    u32 r = 0x7fffu + ((v.i >> 16) & 1u);
    return (u16)((v.i + r) >> 16);
}
__device__ __forceinline__ float silu_(float v) { return v / (1.f + __expf(-v)); }
__device__ __forceinline__ float loadf(const void* p, size_t i, int f32) {
    return f32 ? ((const float*)p)[i] : b2f(((const u16*)p)[i]);
}
__device__ __forceinline__ int loadseg(const int* seg, int n, int i64) {
    return i64 ? seg[2 * n] : seg[n];
}

// ---------------- K1: dtype detect + uvec prep ----------------
__global__ __launch_bounds__(256) void k_prep(const u16* __restrict__ xr,
                                              const int* __restrict__ seg,
                                              const void* __restrict__ Wq,
                                              const void* __restrict__ bq,
                                              const void* __restrict__ Wk,
                                              u32* __restrict__ flag,
                                              float* __restrict__ uvec) {
    int t = threadIdx.x;
    __shared__ int redw[256], redz[256];
    int weird = 0;
    #pragma unroll
    for (int i = 0; i < 16; ++i) {
        u16 u = xr[t * 16 + i];
        u32 e = (u >> 7) & 0xFF;
        weird += (e >= 0xC0) ? 1 : 0;
    }
    redw[t] = weird;
    redz[t] = (seg[2 * t + 1] == 0) ? 1 : 0;
    __syncthreads();
    for (int s = 128; s > 0; s >>= 1) {
        if (t < s) { redw[t] += redw[t + s]; redz[t] += redz[t + s]; }
        __syncthreads();
    }
    u32 fl = ((redw[0] > 64) ? 1u : 0u) | ((redz[0] >= 200) ? 2u : 0u);
    if (blockIdx.x == 0 && t == 0) flag[0] = fl;
    int f32 = (int)(fl & 1u);
    int j = t;
    int f0 = blockIdx.x * 8;
    float acc = 0.f;
    for (int f = f0; f < f0 + 8; ++f)
        acc += loadf(Wk, f, f32) * loadf(Wq, (size_t)f * F + j, f32);
    atomicAdd(&uvec[j], acc);
    if (blockIdx.x == 0) {
        __shared__ float red[256];
        red[j] = loadf(Wk, j, f32) * loadf(bq, j, f32);
        __syncthreads();
        for (int s = 128; s > 0; s >>= 1) {
            if (j < s) red[j] += red[j + s];
            __syncthreads();
        }
        if (j == 0) uvec[F] = red[0];
    }
}

// ---------------- K2: dot + softplus -> astash; LDS-combined atomics ----------------
template <int DT>
__device__ void dot_body(const char* __restrict__ x, const void* __restrict__ E,
                         const int* __restrict__ seg, int i64,
                         const float* __restrict__ uvec, float* __restrict__ astash,
                         float* __restrict__ anorm, u32* __restrict__ amax,
                         int N, int B, int cpb) {
    __shared__ float l_an[WIN];
    __shared__ u32   l_am[WIN];
    const int tid = threadIdx.x;
    const int ngrp = (N + 3) >> 2;
    const int gstart = blockIdx.x * cpb;
    if (gstart >= ngrp) return;                 // uniform whole-block exit
    const int gend = (gstart + cpb < ngrp) ? gstart + cpb : ngrp;
    for (int i = tid; i < WIN; i += 256) { l_an[i] = 0.f; l_am[i] = 0u; }
    const int bbase = loadseg(seg, gstart * 4, i64);
    __syncthreads();

    const int lane = tid & 63;
    const int o = lane & 15, g = lane >> 4;
    const int wvb = tid >> 6;                   // wave in block 0..3
    float uf[16];
    if (DT) {
        #pragma unroll
        for (int i = 0; i < 4; ++i)
            *(float4*)&uf[i * 4] = *(const float4*)(uvec + (o + 16 * i) * 4);
    } else {
        #pragma unroll
        for (int i = 0; i < 2; ++i) {
            int eo = (o + 16 * i) * 8;
            *(float4*)&uf[i * 8]     = *(const float4*)(uvec + eo);
            *(float4*)&uf[i * 8 + 4] = *(const float4*)(uvec + eo + 4);
        }
    }
    const float c0 = uvec[F];
    const size_t rowbytes = (size_t)F * (DT ? 4 : 2);

    #pragma unroll 2
    for (int grp = gstart + wvb; grp < gend; grp += 4) {
        const int row = grp * 4 + g;
        float s = 0.f;
        if (row < N) {
            const char* rp = x + (size_t)row * rowbytes;
            if (DT) {
                #pragma unroll
                for (int i = 0; i < 4; ++i) {
                    float4 v = *(const float4*)(rp + (size_t)(o + 16 * i) * 16);
                    s += v.x * uf[i*4] + v.y * uf[i*4+1] + v.z * uf[i*4+2] + v.w * uf[i*4+3];
                }
            } else {
                #pragma unroll
                for (int i = 0; i < 2; ++i) {
                    uint4 v = *(const uint4*)(rp + (size_t)(o + 16 * i) * 16);
                    const u32 w[4] = {v.x, v.y, v.z, v.w};
                    #pragma unroll
                    for (int k = 0; k < 4; ++k) {
                        s += b2f((u16)(w[k] & 0xffff)) * uf[i*8 + 2*k];
                        s += b2f((u16)(w[k] >> 16))    * uf[i*8 + 2*k + 1];
                    }
                }
            }
        }
        s += __shfl_xor(s, 1, 64);
        s += __shfl_xor(s, 2, 64);
        s += __shfl_xor(s, 4, 64);
        s += __shfl_xor(s, 8, 64);
        float a = 0.f; int b = 0x7fffffff;
        if (o == 0 && row < N) {
            b = loadseg(seg, row, i64);
            float e = fabsf(loadf(E, b, DT));
            float dot = (e / fmaxf(e, 1.f)) * (s + c0) * 0.0625f;
            a = fmaxf(dot, 0.f) + log1pf(expf(-fabsf(dot)));
            astash[row] = a;
        }
        // segmented suffix-combine across the 4 owner lanes (seg sorted)
        float rs = a, rm = a;
        #pragma unroll
        for (int off = 16; off <= 32; off <<= 1) {
            float rs2 = __shfl_down(rs, off, 64);
            float rm2 = __shfl_down(rm, off, 64);
            int   b2  = __shfl_down(b, off, 64);
            if (lane + off < 64 && b2 == b) { rs += rs2; rm = fmaxf(rm, rm2); }
        }
        int bprev = __shfl_up(b, 16, 64);
        if (o == 0 && row < N && (g == 0 || bprev != b)) {
            int rel = b - bbase;
            if (rel >= 0 && rel < WIN) {        // LDS window (block spans ~100 rows)
                atomicAdd(&l_an[rel], rs);
                atomicMax(&l_am[rel], __float_as_uint(rm));
            } else {                            // freak empty-batch jump: direct
                atomicAdd(&anorm[b], rs);
                atomicMax(&amax[b], __float_as_uint(rm));
            }
        }
    }

    __syncthreads();
    for (int i = tid; i < WIN; i += 256) {
        float v = l_an[i]; u32 m = l_am[i];
        if ((v != 0.f || m != 0u) && (bbase + i) < B) {
            atomicAdd(&anorm[bbase + i], v);
            atomicMax(&amax[bbase + i], m);
        }
    }
}

__global__ __launch_bounds__(256) void k_dot(const void* x, const void* E,
                                             const int* seg, const u32* flag,
                                             const float* uvec, float* astash,
                                             float* anorm, u32* amax,
                                             int N, int B, int cpb) {
    u32 fl = flag[0];
    if (fl & 1u) dot_body<1>((const char*)x, E, seg, (int)(fl >> 1), uvec, astash, anorm, amax, N, B, cpb);
    else         dot_body<0>((const char*)x, E, seg, (int)(fl >> 1), uvec, astash, anorm, amax, N, B, cpb);
}

// ---------------- K3: table build (+ per-block redundant cmax prologue) ----------------
template <int DT>
__device__ __forceinline__ void matvec(const void* __restrict__ W, size_t off,
                                       const float4* __restrict__ act, float* g) {
    #pragma unroll 4
    for (int f8 = 0; f8 < F; f8 += 8) {
        float w[8];
        if (DT) {
            const float* Wf = (const float*)W + off + f8;
            float4 w0 = *(const float4*)Wf;
            float4 w1 = *(const float4*)(Wf + 4);
            w[0] = w0.x; w[1] = w0.y; w[2] = w0.z; w[3] = w0.w;
            w[4] = w1.x; w[5] = w1.y; w[6] = w1.z; w[7] = w1.w;
        } else {
            uint4 wv = *(const uint4*)((const u16*)W + off + f8);
            w[0] = b2f((u16)(wv.x & 0xffff)); w[1] = b2f((u16)(wv.x >> 16));
            w[2] = b2f((u16)(wv.y & 0xffff)); w[3] = b2f((u16)(wv.y >> 16));
            w[4] = b2f((u16)(wv.z & 0xffff)); w[5] = b2f((u16)(wv.z >> 16));
            w[6] = b2f((u16)(wv.w & 0xffff)); w[7] = b2f((u16)(wv.w >> 16));
        }
        #pragma unroll
        for (int q = 0; q < 8; ++q) {
            float4 a = act[f8 + q];
            g[0] += a.x * w[q]; g[1] += a.y * w[q];
            g[2] += a.z * w[q]; g[3] += a.w * w[q];
        }
    }
}

template <int DT>
__device__ void table_body(const void* Wv, const void* W1, const void* W2,
                           const void* Wo, float cmax, float* table, int R, int mtab) {
    int j = threadIdx.x;
    int i0 = blockIdx.x * PTS;
    __shared__ float4 actA[F];
    __shared__ float4 actB[F];
    float h[PTS], g[PTS];
    float wvj = loadf(Wv, j, DT);
    #pragma unroll
    for (int p = 0; p < PTS; ++p)
        h[p] = cmax * ((float)(i0 + p) / (float)(mtab - 1)) * wvj;
    for (int r = 0; r < R; ++r) {
        size_t o = (size_t)r * F * F + (size_t)j * F;
        actA[j] = make_float4(silu_(h[0]), silu_(h[1]), silu_(h[2]), silu_(h[3]));
        __syncthreads();
        #pragma unroll
        for (int p = 0; p < PTS; ++p) g[p] = 0.f;
        matvec<DT>(W1, o, actA, g);
        actB[j] = make_float4(silu_(g[0]), silu_(g[1]), silu_(g[2]), silu_(g[3]));
        __syncthreads();
        matvec<DT>(W2, o, actB, h);
        __syncthreads();
    }
    actA[j] = make_float4(silu_(h[0]), silu_(h[1]), silu_(h[2]), silu_(h[3]));
    __syncthreads();
    #pragma unroll
    for (int p = 0; p < PTS; ++p) g[p] = 0.f;
    matvec<DT>(Wo, (size_t)j * F, actA, g);
    #pragma unroll
    for (int p = 0; p < PTS; ++p) table[(size_t)(i0 + p) * F + j] = g[p];
}

__global__ __launch_bounds__(256) void k_table(const void* Wv, const void* W1,
                                               const void* W2, const void* Wo,
                                               const void* __restrict__ E,
                                               const u32* __restrict__ flag,
                                               const float* __restrict__ anorm,
                                               const u32* __restrict__ amax,
                                               u32* __restrict__ cmaxu,
                                               float* __restrict__ table,
                                               int R, int mtab, int B) {
    __shared__ float red[256];
    int tid = threadIdx.x;
    u32 fl = flag[0];
    int f32 = (int)(fl & 1u);
    // per-block redundant cmax: identical loop order in every block -> bit-identical
    float m = 0.f;
    for (int b = tid; b < B; b += 256)
        m = fmaxf(m, __uint_as_float(amax[b]) * fabsf(loadf(E, b, f32)) / (anorm[b] + 1e-8f));
    red[tid] = m;
    __syncthreads();
    for (int s = 128; s > 0; s >>= 1) {
        if (tid < s) red[tid] = fmaxf(red[tid], red[tid + s]);
        __syncthreads();
    }
    float cmax = red[0];
    __syncthreads();                            // red reuse safety before table LDS
    if (blockIdx.x == 0 && tid == 0) cmaxu[0] = __float_as_uint(cmax);
    if (f32) table_body<1>(Wv, W1, W2, Wo, cmax, table, R, mtab);
    else     table_body<0>(Wv, W1, W2, Wo, cmax, table, R, mtab);
}

// ---------------- K4: lerp + full-row write (pure write-only out) ----------------
template <int DT>
__device__ void out_body(const void* __restrict__ E, const int* __restrict__ seg,
                         int i64, const float* __restrict__ anorm,
                         const float* __restrict__ astash,
                         const float* __restrict__ table, float cmax,
                         char* __restrict__ out, int N, int mtab, int cpb) {
    const int tid = threadIdx.x;
    const int lane = tid & 63;
    const int o = lane & 15, g = lane >> 4;
    const int wvb = tid >> 6;
    const int ngrp = (N + 3) >> 2;
    const int gstart = blockIdx.x * cpb;
    if (gstart >= ngrp) return;
    const int gend = (gstart + cpb < ngrp) ? gstart + cpb : ngrp;
    const size_t rowbytes = (size_t)F * (DT ? 4 : 2);
    for (int grp = gstart + wvb; grp < gend; grp += 4) {
        const int row = grp * 4 + g;
        if (row >= N) continue;
        char* rp = out + (size_t)row * rowbytes;
        float a = astash[row];
        int b = loadseg(seg, row, i64);
        float e = fabsf(loadf(E, b, DT));
        float c = a * e / (anorm[b] + 1e-8f);
        float pos = (cmax > 0.f) ? (c / cmax) * (float)(mtab - 1) : 0.f;
        pos = fminf(fmaxf(pos, 0.f), (float)(mtab - 1));
        int idx = (int)pos;
        if (idx > mtab - 2) idx = mtab - 2;
        float fr = pos - (float)idx;
        const float* t0 = table + (size_t)idx * F;
        const float* t1 = t0 + F;
        if (DT) {
            #pragma unroll
            for (int i = 0; i < 4; ++i) {
                int eo = (o + 16 * i) * 4;
                float4 u0 = *(const float4*)(t0 + eo);
                float4 u1 = *(const float4*)(t1 + eo);
                float4 ov;
                ov.x = u0.x + fr * (u1.x - u0.x);
                ov.y = u0.y + fr * (u1.y - u0.y);
                ov.z = u0.z + fr * (u1.z - u0.z);
                ov.w = u0.w + fr * (u1.w - u0.w);
                *(float4*)(rp + (size_t)eo * 4) = ov;
            }
        } else {
            #pragma unroll
            for (int i = 0; i < 2; ++i) {
                int eo = (o + 16 * i) * 8;
                float4 u0 = *(const float4*)(t0 + eo);
                float4 u1 = *(const float4*)(t1 + eo);
                float4 v0 = *(const float4*)(t0 + eo + 4);
                float4 v1 = *(const float4*)(t1 + eo + 4);
                uint4 ov;
                ov.x = (u32)f2b(u0.x + fr * (u1.x - u0.x)) | ((u32)f2b(u0.y + fr * (u1.y - u0.y)) << 16);
                ov.y = (u32)f2b(u0.z + fr * (u1.z - u0.z)) | ((u32)f2b(u0.w + fr * (u1.w - u0.w)) << 16);
                ov.z = (u32)f2b(v0.x + fr * (v1.x - v0.x)) | ((u32)f2b(v0.y + fr * (v1.y - v0.y)) << 16);
                ov.w = (u32)f2b(v0.z + fr * (v1.z - v0.z)) | ((u32)f2b(v0.w + fr * (v1.w - v0.w)) << 16);
                *(uint4*)(rp + (size_t)eo * 2) = ov;
            }
        }
    }
}

__global__ __launch_bounds__(256) void k_out(const void* E, const int* seg,
                                             const u32* flag, const float* anorm,
                                             const float* astash, const float* table,
                                             const u32* cmaxu, void* out,
                                             int N, int mtab, int cpb) {
    u32 fl = flag[0];
    float cmax = __uint_as_float(cmaxu[0]);
    if (fl & 1u) out_body<1>(E, seg, (int)(fl >> 1), anorm, astash, table, cmax, (char*)out, N, mtab, cpb);
    else         out_body<0>(E, seg, (int)(fl >> 1), anorm, astash, table, cmax, (char*)out, N, mtab, cpb);
}

// ==================== host launcher ====================
extern "C" void kernel_launch(void* const* d_in, const int* in_sizes, int n_in,
                              void* d_out, int out_size, void* d_ws, size_t ws_size,
                              hipStream_t stream) {
    int si = (in_sizes[2] == 1) ? 3 : 2;  // batch_seg index (scalar may be dropped)
    const void* x   = d_in[0];
    const void* E   = d_in[1];
    const int* seg  = (const int*)d_in[si];
    const void* Wq  = d_in[si + 1];
    const void* bq  = d_in[si + 2];
    const void* Wk  = d_in[si + 3];
    const void* Wv  = d_in[si + 4];
    const void* W1  = d_in[si + 5];
    const void* W2  = d_in[si + 6];
    const void* Wo  = d_in[si + 7];

    const int B = in_sizes[1];
    const int N = in_sizes[0] / F;
    const int R = in_sizes[si + 5] / (F * F);

    float* ws    = (float*)d_ws;
    float* uvec  = ws;                    // [0..257)
    u32*   cmaxu = (u32*)ws + 258;
    u32*   flag  = (u32*)ws + 259;
    float* anorm = ws + 512;              // B floats
    u32*   amax  = (u32*)ws + 512 + B;    // B u32
    size_t zwords = (size_t)(512 + 2 * B + 64);   // memset extent
    size_t aoff  = (zwords + 8191) & ~(size_t)8191;     // astash offset (words)
    float* astash = ws + aoff;            // N floats
    size_t tof   = aoff + (((size_t)N + 255) & ~(size_t)255);
    float* table = ws + tof;

    size_t avail = (ws_size > tof * 4) ? ws_size - tof * 4 : 0;
    int mtab = 1024;
    while (mtab > 32 && (size_t)mtab * F * sizeof(float) > avail) mtab >>= 1;

    (void)hipMemsetAsync(ws, 0, zwords * 4, stream);  // zeroes uvec, cmax, flag, anorm, amax
    k_prep<<<32, 256, 0, stream>>>((const u16*)x, seg, Wq, bq, Wk, flag, uvec);

    const int ngrp = (N + 3) / 4;
    int blocks = 2048; if (blocks > ngrp) blocks = ngrp;
    const int cpb = (ngrp + blocks - 1) / blocks;

    k_dot<<<blocks, 256, 0, stream>>>(x, E, seg, flag, uvec, astash, anorm, amax, N, B, cpb);
    k_table<<<mtab / PTS, 256, 0, stream>>>(Wv, W1, W2, Wo, E, flag, anorm, amax, cmaxu, table, R, mtab, B);
    k_out<<<blocks, 256, 0, stream>>>(E, seg, flag, anorm, astash, table, cmaxu, d_out, N, mtab, cpb);
}